// Round 12
// baseline (172.766 us; speedup 1.0000x reference)
//
#include <hip/hip_runtime.h>

#define N_NODES 50000
#define E_EDGES 800000
#define M_TOTAL (E_EDGES + N_NODES)
#define IN_DIM 128
#define HEADS 4
#define OUT_DIM 32
#define TOT 128
#define LN_EPS 1e-5f
#define NEG_SLOPE 0.2f
#define LOG2E 1.4426950408889634f

#define SCAN_NBLK ((N_NODES + 255) / 256)          // 196
#define GEMM_NBLK ((N_NODES + 63) / 64)            // 782
#define HIST_NBLK 64
#define EPB 13312                                   // edges/hist block (%4==0); 64*13312 >= M
#define SEPB (EPB / 8)                              // 1664 edges per scatter unit (%4==0)
#define SCAT_NBLK (HIST_NBLK * 8)                   // 512

typedef __bf16 bf16x8 __attribute__((ext_vector_type(8)));
typedef float  f32x4  __attribute__((ext_vector_type(4)));
typedef _Float16 h2   __attribute__((ext_vector_type(2)));

// intra-quad butterfly sum via DPP (no lgkm waits on the critical path)
__device__ __forceinline__ float quad_sum(float p) {
    p += __int_as_float(__builtin_amdgcn_update_dpp(
        0, __float_as_int(p), 0xB1 /*quad_perm[1,0,3,2]*/, 0xF, 0xF, true));
    p += __int_as_float(__builtin_amdgcn_update_dpp(
        0, __float_as_int(p), 0x4E /*quad_perm[2,3,0,1]*/, 0xF, 0xF, true));
    return p;
}

// ---------------- 1. WT build (blocks 0..63) + nibble-LDS hist (64..127) ---
// (r10 verbatim) + block 0 zeroes the scan lookback flags.
__global__ __launch_bounds__(256) void wthist_kernel(
    const int* __restrict__ dsts,
    const float* __restrict__ Wl, const float* __restrict__ Wr,
    unsigned* __restrict__ WT, unsigned char* __restrict__ HP,
    unsigned char* __restrict__ rank8, unsigned* __restrict__ pub) {
    __shared__ unsigned cnt[N_NODES / 8];   // 6250 u32 = 25 KB (8 nibbles/word)
    const int b = blockIdx.x, t = threadIdx.x;
    if (b < 64) {
        if (b == 0 && t < SCAN_NBLK) pub[t] = 0;   // lookback flags
        const int u = b * 256 + t;          // 0..16383
        const int col = u >> 6, k2 = u & 63;
        const float* __restrict__ W = (col < 128) ? Wl : Wr;
        const int c = col & 127;
        union { __bf16 bb[2]; unsigned uu; } p;
        p.bb[0] = (__bf16)W[(2 * k2) * TOT + c];
        p.bb[1] = (__bf16)W[(2 * k2 + 1) * TOT + c];
        WT[col * 64 + k2] = p.uu;
        return;
    }
    const int hb = b - 64;
    const int m_begin = hb * EPB;
    const int m_end = min(m_begin + EPB, M_TOTAL);   // both %4 == 0
    for (int i = t; i < N_NODES / 8; i += 256) cnt[i] = 0;
    __syncthreads();
    for (int m0 = m_begin + t * 4; m0 < m_end; m0 += 1024) {
        int d[4];
        if (m0 < E_EDGES) {                 // E%4==0, m0%4==0: no straddle
            const int4 dv = *(const int4*)&dsts[m0];
            d[0] = dv.x; d[1] = dv.y; d[2] = dv.z; d[3] = dv.w;
        } else {
            d[0] = m0 - E_EDGES; d[1] = d[0] + 1; d[2] = d[0] + 2; d[3] = d[0] + 3;
        }
        uchar4 r;
        unsigned old, sh;
        sh = (d[0] & 7) * 4; old = atomicAdd(&cnt[d[0] >> 3], 1u << sh);
        r.x = (unsigned char)((old >> sh) & 15u);
        sh = (d[1] & 7) * 4; old = atomicAdd(&cnt[d[1] >> 3], 1u << sh);
        r.y = (unsigned char)((old >> sh) & 15u);
        sh = (d[2] & 7) * 4; old = atomicAdd(&cnt[d[2] >> 3], 1u << sh);
        r.z = (unsigned char)((old >> sh) & 15u);
        sh = (d[3] & 7) * 4; old = atomicAdd(&cnt[d[3] >> 3], 1u << sh);
        r.w = (unsigned char)((old >> sh) & 15u);
        *(uchar4*)&rank8[m0] = r;
    }
    __syncthreads();
    // dump nibbles -> bytes, 8 B per thread-iter, coalesced
    unsigned* __restrict__ Hrow = (unsigned*)(HP + (size_t)hb * N_NODES);
    for (int i = t; i < N_NODES / 8; i += 256) {
        const unsigned w = cnt[i];
        const unsigned lo = (w & 15u) | (((w >> 4) & 15u) << 8) |
                            (((w >> 8) & 15u) << 16) | (((w >> 12) & 15u) << 24);
        const unsigned hi = ((w >> 16) & 15u) | (((w >> 20) & 15u) << 8) |
                            (((w >> 24) & 15u) << 16) | (((w >> 28) & 15u) << 24);
        *(uint2*)&Hrow[2 * i] = make_uint2(lo, hi);
    }
}

// ---------------- 2. scan (fused): column prefix + decoupled lookback ------
// One kernel replaces scan1+scan23. Block publishes (total+1) as a single
// atomic word (flag and value share one atomicity unit; total+1 >= 1 so 0
// means "not ready"). All 196 blocks are trivially co-resident -> spin is
// deadlock-free. Device-scope atomics per G16.
__global__ __launch_bounds__(256) void scan_kernel(
    unsigned char* __restrict__ HP, int* __restrict__ rowptr,
    unsigned* __restrict__ pub, unsigned short* __restrict__ sorted16) {
    __shared__ int sh[256];
    const int t = threadIdx.x, bid = blockIdx.x;
    const int i = bid * 256 + t;
    int tot = 0;
    if (i < N_NODES) {
        int run = 0;
#pragma unroll 16
        for (int b = 0; b < HIST_NBLK; ++b) {
            const int h = HP[(size_t)b * N_NODES + i];
            HP[(size_t)b * N_NODES + i] = (unsigned char)run;
            run += h;
        }
        tot = run;
    }
    sh[t] = tot;
    __syncthreads();
#pragma unroll
    for (int off = 1; off < 256; off <<= 1) {
        int u = (t >= off) ? sh[t - off] : 0;
        __syncthreads();
        sh[t] += u;
        __syncthreads();
    }
    const int excl = sh[t] - tot;           // block-exclusive prefix
    if (t == 255) atomicExch(&pub[bid], (unsigned)(sh[255] + 1));  // publish
    // lookback: each thread polls at most one predecessor (bid <= 195 < 256)
    int part = 0;
    for (int j = t; j < bid; j += 256) {
        unsigned v;
        do { v = atomicAdd(&pub[j], 0u); } while (v == 0u);
        part += (int)v - 1;
    }
    __syncthreads();                        // sh scan values all consumed
    sh[t] = part;
    __syncthreads();
#pragma unroll
    for (int off = 128; off >= 1; off >>= 1) {
        if (t < off) sh[t] += sh[t + off];
        __syncthreads();
    }
    const int blockOff = sh[0];
    if (i < N_NODES) rowptr[i] = excl + blockOff;
    if (i == 0) rowptr[N_NODES] = M_TOTAL;
    if (bid == 0 && t < 32) sorted16[M_TOTAL + t] = 0;  // safety pad
}

// ---------------- 3. fused: GEMM (blocks 0..781) + scatter (782..1293) -----
// (r11 verbatim) Scatter LDS-free; each unit confined to one partition's
// 50 KB HP slice (L1/L2-resident). gemm keeps r8-proven 34.3 KB LDS body.
__global__ __launch_bounds__(256) void gemmscatter_kernel(
    const float* __restrict__ x, const unsigned* __restrict__ WT,
    const float* __restrict__ bl, const float* __restrict__ br,
    unsigned* __restrict__ xlb, unsigned* __restrict__ xrb,
    const int* __restrict__ srcs, const int* __restrict__ dsts,
    const int* __restrict__ rowptr, const unsigned char* __restrict__ P,
    const unsigned char* __restrict__ rank8,
    unsigned short* __restrict__ sorted16) {
    __shared__ float epi[4][16][66];        // 16.9 KB
    __shared__ unsigned Bs[64][68];         // 17.4 KB, pitch 68 for banks
    const int t = threadIdx.x;
    if (blockIdx.x >= GEMM_NBLK) {
        const int sb = blockIdx.x - GEMM_NBLK;   // 0..511
        const int hb = sb >> 3;                  // partition 0..63
        const unsigned char* __restrict__ Pb = P + (size_t)hb * N_NODES;
        const int eb = hb * EPB + (sb & 7) * SEPB;
        const int ee = min(eb + SEPB, M_TOTAL);
        for (int m0 = eb + t * 4; m0 < ee; m0 += 1024) {
            int s[4], d[4];
            if (m0 < E_EDGES) {              // E%4==0, m0%4==0: no straddle
                const int4 sv = *(const int4*)&srcs[m0];
                const int4 dv = *(const int4*)&dsts[m0];
                s[0] = sv.x; s[1] = sv.y; s[2] = sv.z; s[3] = sv.w;
                d[0] = dv.x; d[1] = dv.y; d[2] = dv.z; d[3] = dv.w;
            } else {
                s[0] = d[0] = m0 - E_EDGES;
                s[1] = d[1] = d[0] + 1; s[2] = d[2] = d[0] + 2; s[3] = d[3] = d[0] + 3;
            }
            const uchar4 r = *(const uchar4*)&rank8[m0];
            sorted16[rowptr[d[0]] + (int)Pb[d[0]] + (int)r.x] = (unsigned short)s[0];
            sorted16[rowptr[d[1]] + (int)Pb[d[1]] + (int)r.y] = (unsigned short)s[1];
            sorted16[rowptr[d[2]] + (int)Pb[d[2]] + (int)r.z] = (unsigned short)s[2];
            sorted16[rowptr[d[3]] + (int)Pb[d[3]] + (int)r.w] = (unsigned short)s[3];
        }
        return;
    }
    // ---- gemm: r8-proven body (B-panel staged in LDS) ----
    const int w = t >> 6, lane = t & 63;
    const int q = lane >> 4, ln = lane & 15;
    const int m0 = blockIdx.x * 64;

    const int row = min(m0 + w * 16 + ln, N_NODES - 1);
    const float* __restrict__ xrow = x + (size_t)row * IN_DIM;
    bf16x8 A[4];
#pragma unroll
    for (int c = 0; c < 4; ++c) {
        const float4 v0 = *(const float4*)&xrow[c * 32 + q * 8];
        const float4 v1 = *(const float4*)&xrow[c * 32 + q * 8 + 4];
        bf16x8 a;
        a[0] = (__bf16)v0.x; a[1] = (__bf16)v0.y; a[2] = (__bf16)v0.z; a[3] = (__bf16)v0.w;
        a[4] = (__bf16)v1.x; a[5] = (__bf16)v1.y; a[6] = (__bf16)v1.z; a[7] = (__bf16)v1.w;
        A[c] = a;
    }

    const int mr = lane >> 2, cg2 = (lane & 3) * 16;   // 16 cols per lane
    const int grow = m0 + w * 16 + mr;
#pragma unroll
    for (int g = 0; g < 4; ++g) {          // 4 column groups of 64
        const int n0 = g * 64;
        __syncthreads();                   // previous g's readers done
        {
            const unsigned* __restrict__ src = WT + n0 * 64;
#pragma unroll
            for (int it = 0; it < 4; ++it) {
                const int dw = t * 4 + it * 1024;     // 4096 dwords total
                const uint4 v = *(const uint4*)&src[dw];
                *(uint4*)&Bs[dw >> 6][dw & 63] = v;
            }
        }
        __syncthreads();
        const float* __restrict__ bvec = (g < 2) ? bl : br;
        f32x4 acc[4];
#pragma unroll
        for (int nt = 0; nt < 4; ++nt) {
            const float b = bvec[(n0 & 127) + nt * 16 + ln];
            acc[nt] = (f32x4){b, b, b, b};
        }
#pragma unroll
        for (int nt = 0; nt < 4; ++nt) {
#pragma unroll
            for (int c = 0; c < 4; ++c) {
                const bf16x8 B = *(const bf16x8*)&Bs[nt * 16 + ln][c * 16 + q * 4];
                acc[nt] = __builtin_amdgcn_mfma_f32_16x16x32_bf16(A[c], B, acc[nt], 0, 0, 0);
            }
        }
        // single-wave LDS repack (in-order DS pipe; same-wave readback)
#pragma unroll
        for (int nt = 0; nt < 4; ++nt)
#pragma unroll
            for (int r = 0; r < 4; ++r)
                epi[w][q * 4 + r][nt * 16 + ln] = acc[nt][r];

        if (grow < N_NODES) {
            unsigned p[8];
#pragma unroll
            for (int i = 0; i < 8; ++i) {
                union { _Float16 h[2]; unsigned u; } pk;
                pk.h[0] = (_Float16)epi[w][mr][cg2 + 2 * i];
                pk.h[1] = (_Float16)epi[w][mr][cg2 + 2 * i + 1];
                p[i] = pk.u;
            }
            unsigned* __restrict__ dst = ((g < 2) ? xlb : xrb) +
                (size_t)grow * 64 + (g & 1) * 32 + (cg2 >> 1);
            *(uint4*)&dst[0] = make_uint4(p[0], p[1], p[2], p[3]);
            *(uint4*)&dst[4] = make_uint4(p[4], p[5], p[6], p[7]);
        }
    }
}

// ============ 4. fused GAT: 2-deep gather pipeline =========================
// r8 structure with the gather double-buffered one extra iteration deep
// (u=consume, v=next, w=in flight; indices 3 iters ahead) to cover the
// 200-900 cyc L2/HBM gather latency that 1-deep (~250 cyc) could not.
__global__ __launch_bounds__(256) void gat_kernel(
    const int* __restrict__ rowptr, const unsigned short* __restrict__ sorted16,
    const unsigned* __restrict__ xlb, const unsigned* __restrict__ xrb,
    const float* __restrict__ att, const float* __restrict__ x,
    const float* __restrict__ bias, const float* __restrict__ g,
    const float* __restrict__ bvec, float* __restrict__ out) {
    const int d = blockIdx.x * 4 + (threadIdx.x >> 6);
    const int lane = threadIdx.x & 63;
    const int ln = lane & 15, q = lane >> 4;
    if (d >= N_NODES) return;

    h2 xrh[4], ath[4];
    {
        const uint4 ur = *(const uint4*)&xrb[(size_t)d * 64 + 4 * ln];
        union { uint4 u; h2 h[4]; } cr; cr.u = ur;
        xrh[0] = cr.h[0]; xrh[1] = cr.h[1]; xrh[2] = cr.h[2]; xrh[3] = cr.h[3];
        const float4 a0 = *(const float4*)&att[8 * ln];
        const float4 a1 = *(const float4*)&att[8 * ln + 4];
        ath[0][0] = (_Float16)(a0.x * LOG2E); ath[0][1] = (_Float16)(a0.y * LOG2E);
        ath[1][0] = (_Float16)(a0.z * LOG2E); ath[1][1] = (_Float16)(a0.w * LOG2E);
        ath[2][0] = (_Float16)(a1.x * LOG2E); ath[2][1] = (_Float16)(a1.y * LOG2E);
        ath[3][0] = (_Float16)(a1.z * LOG2E); ath[3][1] = (_Float16)(a1.w * LOG2E);
    }
    const h2 slope = (h2){(_Float16)NEG_SLOPE, (_Float16)NEG_SLOPE};
    const int beg = rowptr[d], end = rowptr[d + 1];

    float l = 0.f;
    h2 acc4[4];
#pragma unroll
    for (int k = 0; k < 4; ++k) acc4[k] = (h2){(_Float16)0.f, (_Float16)0.f};

    // prologue: iters 0 and 1 gathers in flight, iter-2 indices loaded
    uint4 u0, u1, v0, v1;
    {
        const int sA0 = (int)sorted16[min(beg + q, end - 1)];
        const int sA1 = (int)sorted16[min(beg + 4 + q, end - 1)];
        u0 = *(const uint4*)&xlb[(size_t)sA0 * 64 + 4 * ln];
        u1 = *(const uint4*)&xlb[(size_t)sA1 * 64 + 4 * ln];
        const int sB0 = (int)sorted16[min(beg + 8 + q, end - 1)];
        const int sB1 = (int)sorted16[min(beg + 12 + q, end - 1)];
        v0 = *(const uint4*)&xlb[(size_t)sB0 * 64 + 4 * ln];
        v1 = *(const uint4*)&xlb[(size_t)sB1 * 64 + 4 * ln];
    }
    int sC0 = (int)sorted16[min(beg + 16 + q, end - 1)];
    int sC1 = (int)sorted16[min(beg + 20 + q, end - 1)];

    for (int base = beg; base < end; base += 8) {
        const int sD0 = (int)sorted16[min(base + 24 + q, end - 1)];
        const int sD1 = (int)sorted16[min(base + 28 + q, end - 1)];
        const uint4 w0 = *(const uint4*)&xlb[(size_t)sC0 * 64 + 4 * ln];
        const uint4 w1 = *(const uint4*)&xlb[(size_t)sC1 * 64 + 4 * ln];

        union { unsigned uu; h2 h; } a0, a1, a2, a3, b0, b1, b2, b3;
        a0.uu = u0.x; a1.uu = u0.y; a2.uu = u0.z; a3.uu = u0.w;
        b0.uu = u1.x; b1.uu = u1.y; b2.uu = u1.z; b3.uu = u1.w;
        h2 mA0 = a0.h + xrh[0], mA1 = a1.h + xrh[1];
        h2 mA2 = a2.h + xrh[2], mA3 = a3.h + xrh[3];
        h2 mB0 = b0.h + xrh[0], mB1 = b1.h + xrh[1];
        h2 mB2 = b2.h + xrh[2], mB3 = b3.h + xrh[3];
        mA0 = __builtin_elementwise_max(mA0, mA0 * slope);
        mA1 = __builtin_elementwise_max(mA1, mA1 * slope);
        mA2 = __builtin_elementwise_max(mA2, mA2 * slope);
        mA3 = __builtin_elementwise_max(mA3, mA3 * slope);
        mB0 = __builtin_elementwise_max(mB0, mB0 * slope);
        mB1 = __builtin_elementwise_max(mB1, mB1 * slope);
        mB2 = __builtin_elementwise_max(mB2, mB2 * slope);
        mB3 = __builtin_elementwise_max(mB3, mB3 * slope);
        float p0 = __builtin_amdgcn_fdot2(mA0, ath[0], 0.0f, false);
        p0 = __builtin_amdgcn_fdot2(mA1, ath[1], p0, false);
        p0 = __builtin_amdgcn_fdot2(mA2, ath[2], p0, false);
        p0 = __builtin_amdgcn_fdot2(mA3, ath[3], p0, false);
        float p1 = __builtin_amdgcn_fdot2(mB0, ath[0], 0.0f, false);
        p1 = __builtin_amdgcn_fdot2(mB1, ath[1], p1, false);
        p1 = __builtin_amdgcn_fdot2(mB2, ath[2], p1, false);
        p1 = __builtin_amdgcn_fdot2(mB3, ath[3], p1, false);
        p0 = quad_sum(p0);                      // per-head score in each quad
        p1 = quad_sum(p1);
        const float e0 = (base + q < end) ? exp2f(p0) : 0.f;
        const float e1 = (base + 4 + q < end) ? exp2f(p1) : 0.f;
        l += e0 + e1;
        const _Float16 eh0 = (_Float16)e0, eh1 = (_Float16)e1;
        const h2 e20 = (h2){eh0, eh0}, e21 = (h2){eh1, eh1};
        acc4[0] += e20 * a0.h; acc4[0] += e21 * b0.h;
        acc4[1] += e20 * a1.h; acc4[1] += e21 * b1.h;
        acc4[2] += e20 * a2.h; acc4[2] += e21 * b2.h;
        acc4[3] += e20 * a3.h; acc4[3] += e21 * b3.h;

        u0 = v0; u1 = v1; v0 = w0; v1 = w1; sC0 = sD0; sC1 = sD1;
    }

    // plain sum combine of the 4 edge-slots (xor lane bits 4, 5)
#pragma unroll
    for (int off = 16; off <= 32; off <<= 1) {
        l += __shfl_xor(l, off, 64);
#pragma unroll
        for (int k = 0; k < 4; ++k) {
            union { h2 h; int i; } tmp; tmp.h = acc4[k];
            tmp.i = __shfl_xor(tmp.i, off, 64);
            acc4[k] += tmp.h;
        }
    }
    float acc[8];
#pragma unroll
    for (int k = 0; k < 4; ++k) {
        acc[2 * k]     = (float)acc4[k][0];
        acc[2 * k + 1] = (float)acc4[k][1];
    }

    // epilogue: normalize, bias, residual, LayerNorm, ELU
    const float inv_l = 1.0f / l;
    const float4 xv0 = *(const float4*)&x[(size_t)d * TOT + 8 * ln];
    const float4 xv1 = *(const float4*)&x[(size_t)d * TOT + 8 * ln + 4];
    const float4 bi0 = *(const float4*)&bias[8 * ln];
    const float4 bi1 = *(const float4*)&bias[8 * ln + 4];
    float v[8];
    v[0] = fmaf(acc[0], inv_l, bi0.x + xv0.x);
    v[1] = fmaf(acc[1], inv_l, bi0.y + xv0.y);
    v[2] = fmaf(acc[2], inv_l, bi0.z + xv0.z);
    v[3] = fmaf(acc[3], inv_l, bi0.w + xv0.w);
    v[4] = fmaf(acc[4], inv_l, bi1.x + xv1.x);
    v[5] = fmaf(acc[5], inv_l, bi1.y + xv1.y);
    v[6] = fmaf(acc[6], inv_l, bi1.z + xv1.z);
    v[7] = fmaf(acc[7], inv_l, bi1.w + xv1.w);
    float sum = 0.f, sq = 0.f;
#pragma unroll
    for (int k = 0; k < 8; ++k) { sum += v[k]; sq = fmaf(v[k], v[k], sq); }
#pragma unroll
    for (int off = 1; off <= 8; off <<= 1) {
        sum += __shfl_xor(sum, off, 64);
        sq  += __shfl_xor(sq,  off, 64);
    }
    const float mu  = sum * (1.0f / TOT);
    const float var = sq * (1.0f / TOT) - mu * mu;
    const float inv = rsqrtf(var + LN_EPS);
    const float4 g0 = *(const float4*)&g[8 * ln];
    const float4 g1 = *(const float4*)&g[8 * ln + 4];
    const float4 b0 = *(const float4*)&bvec[8 * ln];
    const float4 b1 = *(const float4*)&bvec[8 * ln + 4];
    float y[8];
    y[0] = (v[0] - mu) * inv * g0.x + b0.x;
    y[1] = (v[1] - mu) * inv * g0.y + b0.y;
    y[2] = (v[2] - mu) * inv * g0.z + b0.z;
    y[3] = (v[3] - mu) * inv * g0.w + b0.w;
    y[4] = (v[4] - mu) * inv * g1.x + b1.x;
    y[5] = (v[5] - mu) * inv * g1.y + b1.y;
    y[6] = (v[6] - mu) * inv * g1.z + b1.z;
    y[7] = (v[7] - mu) * inv * g1.w + b1.w;
#pragma unroll
    for (int k = 0; k < 8; ++k) y[k] = y[k] > 0.f ? y[k] : __expf(y[k]) - 1.f;
    if (q < 2) {
        float4 o = (q == 0) ? make_float4(y[0], y[1], y[2], y[3])
                            : make_float4(y[4], y[5], y[6], y[7]);
        *(float4*)&out[(size_t)d * TOT + 8 * ln + 4 * q] = o;
    }
}

extern "C" void kernel_launch(void* const* d_in, const int* in_sizes, int n_in,
                              void* d_out, int out_size, void* d_ws, size_t ws_size,
                              hipStream_t stream) {
    const float* x    = (const float*)d_in[0];
    const int*   ei   = (const int*)d_in[1];
    const float* Wl   = (const float*)d_in[2];
    const float* bl   = (const float*)d_in[3];
    const float* Wr   = (const float*)d_in[4];
    const float* br   = (const float*)d_in[5];
    const float* att  = (const float*)d_in[6];
    const float* bias = (const float*)d_in[7];
    const float* ln_g = (const float*)d_in[8];
    const float* ln_b = (const float*)d_in[9];
    const int* srcs = ei;
    const int* dsts = ei + E_EDGES;

    unsigned* xlb = (unsigned*)d_ws;                          // N*64 dwords (f16 pairs)
    unsigned* xrb = xlb + (size_t)N_NODES * 64;               // N*64 dwords (f16 pairs)
    int*   rowptr     = (int*)(xrb + (size_t)N_NODES * 64);   // N+1
    unsigned* pub     = (unsigned*)(rowptr + N_NODES + 1);    // 196 lookback words (+pad)
    unsigned* WT      = (unsigned*)(pub + SCAN_NBLK + 3);     // 256*64 dwords (8B-aligned)
    unsigned char* HP = (unsigned char*)(WT + 256 * 64);      // 64*N u8 (3.2 MB)
    unsigned short* sorted16 = (unsigned short*)(HP + (size_t)HIST_NBLK * N_NODES); // M+32 u16
    unsigned char*  rank8    = (unsigned char*)(sorted16 + M_TOTAL + 32);           // M u8

    wthist_kernel<<<64 + HIST_NBLK, 256, 0, stream>>>(dsts, Wl, Wr, WT, HP, rank8, pub);
    scan_kernel<<<SCAN_NBLK, 256, 0, stream>>>(HP, rowptr, pub, sorted16);
    gemmscatter_kernel<<<GEMM_NBLK + SCAT_NBLK, 256, 0, stream>>>(
        x, WT, bl, br, xlb, xrb, srcs, dsts, rowptr, HP, rank8, sorted16);
    gat_kernel<<<(N_NODES + 3) / 4, 256, 0, stream>>>(rowptr, sorted16, xlb, xrb, att, x,
                                                      bias, ln_g, ln_b, (float*)d_out);
}

// Round 13
// 170.699 us; speedup vs baseline: 1.0121x; 1.0121x over previous
//
#include <hip/hip_runtime.h>

#define N_NODES 50000
#define E_EDGES 800000
#define M_TOTAL (E_EDGES + N_NODES)
#define IN_DIM 128
#define HEADS 4
#define OUT_DIM 32
#define TOT 128
#define LN_EPS 1e-5f
#define NEG_SLOPE 0.2f
#define LOG2E 1.4426950408889634f

#define SCAN_NBLK ((N_NODES + 255) / 256)          // 196
#define GEMM_NBLK ((N_NODES + 63) / 64)            // 782
#define HIST_NBLK 64
#define EPB 13312                                   // edges/hist block (%4==0); 64*13312 >= M
#define SEPB (EPB / 8)                              // 1664 edges per scatter unit (%4==0)
#define SCAT_NBLK (HIST_NBLK * 8)                   // 512

typedef __bf16 bf16x8 __attribute__((ext_vector_type(8)));
typedef float  f32x4  __attribute__((ext_vector_type(4)));
typedef _Float16 h2   __attribute__((ext_vector_type(2)));

// intra-quad butterfly sum via DPP (no lgkm waits on the critical path)
__device__ __forceinline__ float quad_sum(float p) {
    p += __int_as_float(__builtin_amdgcn_update_dpp(
        0, __float_as_int(p), 0xB1 /*quad_perm[1,0,3,2]*/, 0xF, 0xF, true));
    p += __int_as_float(__builtin_amdgcn_update_dpp(
        0, __float_as_int(p), 0x4E /*quad_perm[2,3,0,1]*/, 0xF, 0xF, true));
    return p;
}

// ---------------- 1. WT build (blocks 0..63) + nibble-LDS hist (64..127) ---
__global__ __launch_bounds__(256) void wthist_kernel(
    const int* __restrict__ dsts,
    const float* __restrict__ Wl, const float* __restrict__ Wr,
    unsigned* __restrict__ WT, unsigned char* __restrict__ HP,
    unsigned char* __restrict__ rank8, unsigned* __restrict__ pub) {
    __shared__ unsigned cnt[N_NODES / 8];   // 6250 u32 = 25 KB (8 nibbles/word)
    const int b = blockIdx.x, t = threadIdx.x;
    if (b < 64) {
        if (b == 0 && t < SCAN_NBLK) pub[t] = 0;   // lookback flags
        const int u = b * 256 + t;          // 0..16383
        const int col = u >> 6, k2 = u & 63;
        const float* __restrict__ W = (col < 128) ? Wl : Wr;
        const int c = col & 127;
        union { __bf16 bb[2]; unsigned uu; } p;
        p.bb[0] = (__bf16)W[(2 * k2) * TOT + c];
        p.bb[1] = (__bf16)W[(2 * k2 + 1) * TOT + c];
        WT[col * 64 + k2] = p.uu;
        return;
    }
    const int hb = b - 64;
    const int m_begin = hb * EPB;
    const int m_end = min(m_begin + EPB, M_TOTAL);   // both %4 == 0
    for (int i = t; i < N_NODES / 8; i += 256) cnt[i] = 0;
    __syncthreads();
    for (int m0 = m_begin + t * 4; m0 < m_end; m0 += 1024) {
        int d[4];
        if (m0 < E_EDGES) {                 // E%4==0, m0%4==0: no straddle
            const int4 dv = *(const int4*)&dsts[m0];
            d[0] = dv.x; d[1] = dv.y; d[2] = dv.z; d[3] = dv.w;
        } else {
            d[0] = m0 - E_EDGES; d[1] = d[0] + 1; d[2] = d[0] + 2; d[3] = d[0] + 3;
        }
        uchar4 r;
        unsigned old, sh;
        sh = (d[0] & 7) * 4; old = atomicAdd(&cnt[d[0] >> 3], 1u << sh);
        r.x = (unsigned char)((old >> sh) & 15u);
        sh = (d[1] & 7) * 4; old = atomicAdd(&cnt[d[1] >> 3], 1u << sh);
        r.y = (unsigned char)((old >> sh) & 15u);
        sh = (d[2] & 7) * 4; old = atomicAdd(&cnt[d[2] >> 3], 1u << sh);
        r.z = (unsigned char)((old >> sh) & 15u);
        sh = (d[3] & 7) * 4; old = atomicAdd(&cnt[d[3] >> 3], 1u << sh);
        r.w = (unsigned char)((old >> sh) & 15u);
        *(uchar4*)&rank8[m0] = r;
    }
    __syncthreads();
    // dump nibbles -> bytes, 8 B per thread-iter, coalesced
    unsigned* __restrict__ Hrow = (unsigned*)(HP + (size_t)hb * N_NODES);
    for (int i = t; i < N_NODES / 8; i += 256) {
        const unsigned w = cnt[i];
        const unsigned lo = (w & 15u) | (((w >> 4) & 15u) << 8) |
                            (((w >> 8) & 15u) << 16) | (((w >> 12) & 15u) << 24);
        const unsigned hi = ((w >> 16) & 15u) | (((w >> 20) & 15u) << 8) |
                            (((w >> 24) & 15u) << 16) | (((w >> 28) & 15u) << 24);
        *(uint2*)&Hrow[2 * i] = make_uint2(lo, hi);
    }
}

// ---------------- 2. scan (fused): column prefix + decoupled lookback ------
__global__ __launch_bounds__(256) void scan_kernel(
    unsigned char* __restrict__ HP, int* __restrict__ rowptr,
    unsigned* __restrict__ pub, unsigned short* __restrict__ sorted16) {
    __shared__ int sh[256];
    const int t = threadIdx.x, bid = blockIdx.x;
    const int i = bid * 256 + t;
    int tot = 0;
    if (i < N_NODES) {
        int run = 0;
#pragma unroll 16
        for (int b = 0; b < HIST_NBLK; ++b) {
            const int h = HP[(size_t)b * N_NODES + i];
            HP[(size_t)b * N_NODES + i] = (unsigned char)run;
            run += h;
        }
        tot = run;
    }
    sh[t] = tot;
    __syncthreads();
#pragma unroll
    for (int off = 1; off < 256; off <<= 1) {
        int u = (t >= off) ? sh[t - off] : 0;
        __syncthreads();
        sh[t] += u;
        __syncthreads();
    }
    const int excl = sh[t] - tot;           // block-exclusive prefix
    if (t == 255) atomicExch(&pub[bid], (unsigned)(sh[255] + 1));  // publish
    int part = 0;
    for (int j = t; j < bid; j += 256) {
        unsigned v;
        do { v = atomicAdd(&pub[j], 0u); } while (v == 0u);
        part += (int)v - 1;
    }
    __syncthreads();                        // sh scan values all consumed
    sh[t] = part;
    __syncthreads();
#pragma unroll
    for (int off = 128; off >= 1; off >>= 1) {
        if (t < off) sh[t] += sh[t + off];
        __syncthreads();
    }
    const int blockOff = sh[0];
    if (i < N_NODES) rowptr[i] = excl + blockOff;
    if (i == 0) rowptr[N_NODES] = M_TOTAL;
    if (bid == 0 && t < 32) sorted16[M_TOTAL + t] = 0;  // safety pad
}

// ---------------- 3. fused: GEMM (blocks 0..781) + scatter (782..1293) -----
__global__ __launch_bounds__(256) void gemmscatter_kernel(
    const float* __restrict__ x, const unsigned* __restrict__ WT,
    const float* __restrict__ bl, const float* __restrict__ br,
    unsigned* __restrict__ xlb, unsigned* __restrict__ xrb,
    const int* __restrict__ srcs, const int* __restrict__ dsts,
    const int* __restrict__ rowptr, const unsigned char* __restrict__ P,
    const unsigned char* __restrict__ rank8,
    unsigned short* __restrict__ sorted16) {
    __shared__ float epi[4][16][66];        // 16.9 KB
    __shared__ unsigned Bs[64][68];         // 17.4 KB, pitch 68 for banks
    const int t = threadIdx.x;
    if (blockIdx.x >= GEMM_NBLK) {
        const int sb = blockIdx.x - GEMM_NBLK;   // 0..511
        const int hb = sb >> 3;                  // partition 0..63
        const unsigned char* __restrict__ Pb = P + (size_t)hb * N_NODES;
        const int eb = hb * EPB + (sb & 7) * SEPB;
        const int ee = min(eb + SEPB, M_TOTAL);
        for (int m0 = eb + t * 4; m0 < ee; m0 += 1024) {
            int s[4], d[4];
            if (m0 < E_EDGES) {              // E%4==0, m0%4==0: no straddle
                const int4 sv = *(const int4*)&srcs[m0];
                const int4 dv = *(const int4*)&dsts[m0];
                s[0] = sv.x; s[1] = sv.y; s[2] = sv.z; s[3] = sv.w;
                d[0] = dv.x; d[1] = dv.y; d[2] = dv.z; d[3] = dv.w;
            } else {
                s[0] = d[0] = m0 - E_EDGES;
                s[1] = d[1] = d[0] + 1; s[2] = d[2] = d[0] + 2; s[3] = d[3] = d[0] + 3;
            }
            const uchar4 r = *(const uchar4*)&rank8[m0];
            sorted16[rowptr[d[0]] + (int)Pb[d[0]] + (int)r.x] = (unsigned short)s[0];
            sorted16[rowptr[d[1]] + (int)Pb[d[1]] + (int)r.y] = (unsigned short)s[1];
            sorted16[rowptr[d[2]] + (int)Pb[d[2]] + (int)r.z] = (unsigned short)s[2];
            sorted16[rowptr[d[3]] + (int)Pb[d[3]] + (int)r.w] = (unsigned short)s[3];
        }
        return;
    }
    // ---- gemm: r8-proven body (B-panel staged in LDS) ----
    const int w = t >> 6, lane = t & 63;
    const int q = lane >> 4, ln = lane & 15;
    const int m0 = blockIdx.x * 64;

    const int row = min(m0 + w * 16 + ln, N_NODES - 1);
    const float* __restrict__ xrow = x + (size_t)row * IN_DIM;
    bf16x8 A[4];
#pragma unroll
    for (int c = 0; c < 4; ++c) {
        const float4 v0 = *(const float4*)&xrow[c * 32 + q * 8];
        const float4 v1 = *(const float4*)&xrow[c * 32 + q * 8 + 4];
        bf16x8 a;
        a[0] = (__bf16)v0.x; a[1] = (__bf16)v0.y; a[2] = (__bf16)v0.z; a[3] = (__bf16)v0.w;
        a[4] = (__bf16)v1.x; a[5] = (__bf16)v1.y; a[6] = (__bf16)v1.z; a[7] = (__bf16)v1.w;
        A[c] = a;
    }

    const int mr = lane >> 2, cg2 = (lane & 3) * 16;   // 16 cols per lane
    const int grow = m0 + w * 16 + mr;
#pragma unroll
    for (int g = 0; g < 4; ++g) {          // 4 column groups of 64
        const int n0 = g * 64;
        __syncthreads();                   // previous g's readers done
        {
            const unsigned* __restrict__ src = WT + n0 * 64;
#pragma unroll
            for (int it = 0; it < 4; ++it) {
                const int dw = t * 4 + it * 1024;     // 4096 dwords total
                const uint4 v = *(const uint4*)&src[dw];
                *(uint4*)&Bs[dw >> 6][dw & 63] = v;
            }
        }
        __syncthreads();
        const float* __restrict__ bvec = (g < 2) ? bl : br;
        f32x4 acc[4];
#pragma unroll
        for (int nt = 0; nt < 4; ++nt) {
            const float b = bvec[(n0 & 127) + nt * 16 + ln];
            acc[nt] = (f32x4){b, b, b, b};
        }
#pragma unroll
        for (int nt = 0; nt < 4; ++nt) {
#pragma unroll
            for (int c = 0; c < 4; ++c) {
                const bf16x8 B = *(const bf16x8*)&Bs[nt * 16 + ln][c * 16 + q * 4];
                acc[nt] = __builtin_amdgcn_mfma_f32_16x16x32_bf16(A[c], B, acc[nt], 0, 0, 0);
            }
        }
        // single-wave LDS repack (in-order DS pipe; same-wave readback)
#pragma unroll
        for (int nt = 0; nt < 4; ++nt)
#pragma unroll
            for (int r = 0; r < 4; ++r)
                epi[w][q * 4 + r][nt * 16 + ln] = acc[nt][r];

        if (grow < N_NODES) {
            unsigned p[8];
#pragma unroll
            for (int i = 0; i < 8; ++i) {
                union { _Float16 h[2]; unsigned u; } pk;
                pk.h[0] = (_Float16)epi[w][mr][cg2 + 2 * i];
                pk.h[1] = (_Float16)epi[w][mr][cg2 + 2 * i + 1];
                p[i] = pk.u;
            }
            unsigned* __restrict__ dst = ((g < 2) ? xlb : xrb) +
                (size_t)grow * 64 + (g & 1) * 32 + (cg2 >> 1);
            *(uint4*)&dst[0] = make_uint4(p[0], p[1], p[2], p[3]);
            *(uint4*)&dst[4] = make_uint4(p[4], p[5], p[6], p[7]);
        }
    }
}

// ============ 4. fused GAT: one dst per 64-thread block ====================
// r11 1-deep inner loop (proven 44.6 us) relaunched as 50000 single-wave
// blocks: each wave retires independently -> Poisson-degree block-tail
// (~+12% from max-of-4-waves) eliminated; scheduler backfills freely.
__global__ __launch_bounds__(64) void gat_kernel(
    const int* __restrict__ rowptr, const unsigned short* __restrict__ sorted16,
    const unsigned* __restrict__ xlb, const unsigned* __restrict__ xrb,
    const float* __restrict__ att, const float* __restrict__ x,
    const float* __restrict__ bias, const float* __restrict__ g,
    const float* __restrict__ bvec, float* __restrict__ out) {
    const int d = blockIdx.x;
    const int lane = threadIdx.x;
    const int ln = lane & 15, q = lane >> 4;

    h2 xrh[4], ath[4];
    {
        const uint4 ur = *(const uint4*)&xrb[(size_t)d * 64 + 4 * ln];
        union { uint4 u; h2 h[4]; } cr; cr.u = ur;
        xrh[0] = cr.h[0]; xrh[1] = cr.h[1]; xrh[2] = cr.h[2]; xrh[3] = cr.h[3];
        const float4 a0 = *(const float4*)&att[8 * ln];
        const float4 a1 = *(const float4*)&att[8 * ln + 4];
        ath[0][0] = (_Float16)(a0.x * LOG2E); ath[0][1] = (_Float16)(a0.y * LOG2E);
        ath[1][0] = (_Float16)(a0.z * LOG2E); ath[1][1] = (_Float16)(a0.w * LOG2E);
        ath[2][0] = (_Float16)(a1.x * LOG2E); ath[2][1] = (_Float16)(a1.y * LOG2E);
        ath[3][0] = (_Float16)(a1.z * LOG2E); ath[3][1] = (_Float16)(a1.w * LOG2E);
    }
    const h2 slope = (h2){(_Float16)NEG_SLOPE, (_Float16)NEG_SLOPE};
    const int beg = rowptr[d], end = rowptr[d + 1];

    float l = 0.f;
    h2 acc4[4];
#pragma unroll
    for (int k = 0; k < 4; ++k) acc4[k] = (h2){(_Float16)0.f, (_Float16)0.f};

    // prologue: iter-0 gathers in flight, iter-1 indices loaded
    uint4 u0, u1;
    {
        const int sA0 = (int)sorted16[min(beg + q, end - 1)];
        const int sA1 = (int)sorted16[min(beg + 4 + q, end - 1)];
        u0 = *(const uint4*)&xlb[(size_t)sA0 * 64 + 4 * ln];
        u1 = *(const uint4*)&xlb[(size_t)sA1 * 64 + 4 * ln];
    }
    int sB0 = (int)sorted16[min(beg + 8 + q, end - 1)];
    int sB1 = (int)sorted16[min(beg + 12 + q, end - 1)];

    for (int base = beg; base < end; base += 8) {
        const int sC0 = (int)sorted16[min(base + 16 + q, end - 1)];
        const int sC1 = (int)sorted16[min(base + 20 + q, end - 1)];
        const uint4 un0 = *(const uint4*)&xlb[(size_t)sB0 * 64 + 4 * ln];
        const uint4 un1 = *(const uint4*)&xlb[(size_t)sB1 * 64 + 4 * ln];

        union { unsigned uu; h2 h; } a0, a1, a2, a3, b0, b1, b2, b3;
        a0.uu = u0.x; a1.uu = u0.y; a2.uu = u0.z; a3.uu = u0.w;
        b0.uu = u1.x; b1.uu = u1.y; b2.uu = u1.z; b3.uu = u1.w;
        h2 mA0 = a0.h + xrh[0], mA1 = a1.h + xrh[1];
        h2 mA2 = a2.h + xrh[2], mA3 = a3.h + xrh[3];
        h2 mB0 = b0.h + xrh[0], mB1 = b1.h + xrh[1];
        h2 mB2 = b2.h + xrh[2], mB3 = b3.h + xrh[3];
        mA0 = __builtin_elementwise_max(mA0, mA0 * slope);
        mA1 = __builtin_elementwise_max(mA1, mA1 * slope);
        mA2 = __builtin_elementwise_max(mA2, mA2 * slope);
        mA3 = __builtin_elementwise_max(mA3, mA3 * slope);
        mB0 = __builtin_elementwise_max(mB0, mB0 * slope);
        mB1 = __builtin_elementwise_max(mB1, mB1 * slope);
        mB2 = __builtin_elementwise_max(mB2, mB2 * slope);
        mB3 = __builtin_elementwise_max(mB3, mB3 * slope);
        float p0 = __builtin_amdgcn_fdot2(mA0, ath[0], 0.0f, false);
        p0 = __builtin_amdgcn_fdot2(mA1, ath[1], p0, false);
        p0 = __builtin_amdgcn_fdot2(mA2, ath[2], p0, false);
        p0 = __builtin_amdgcn_fdot2(mA3, ath[3], p0, false);
        float p1 = __builtin_amdgcn_fdot2(mB0, ath[0], 0.0f, false);
        p1 = __builtin_amdgcn_fdot2(mB1, ath[1], p1, false);
        p1 = __builtin_amdgcn_fdot2(mB2, ath[2], p1, false);
        p1 = __builtin_amdgcn_fdot2(mB3, ath[3], p1, false);
        p0 = quad_sum(p0);                      // per-head score in each quad
        p1 = quad_sum(p1);
        const float e0 = (base + q < end) ? exp2f(p0) : 0.f;
        const float e1 = (base + 4 + q < end) ? exp2f(p1) : 0.f;
        l += e0 + e1;
        const _Float16 eh0 = (_Float16)e0, eh1 = (_Float16)e1;
        const h2 e20 = (h2){eh0, eh0}, e21 = (h2){eh1, eh1};
        acc4[0] += e20 * a0.h; acc4[0] += e21 * b0.h;
        acc4[1] += e20 * a1.h; acc4[1] += e21 * b1.h;
        acc4[2] += e20 * a2.h; acc4[2] += e21 * b2.h;
        acc4[3] += e20 * a3.h; acc4[3] += e21 * b3.h;

        u0 = un0; u1 = un1; sB0 = sC0; sB1 = sC1;
    }

    // plain sum combine of the 4 edge-slots (xor lane bits 4, 5)
#pragma unroll
    for (int off = 16; off <= 32; off <<= 1) {
        l += __shfl_xor(l, off, 64);
#pragma unroll
        for (int k = 0; k < 4; ++k) {
            union { h2 h; int i; } tmp; tmp.h = acc4[k];
            tmp.i = __shfl_xor(tmp.i, off, 64);
            acc4[k] += tmp.h;
        }
    }
    float acc[8];
#pragma unroll
    for (int k = 0; k < 4; ++k) {
        acc[2 * k]     = (float)acc4[k][0];
        acc[2 * k + 1] = (float)acc4[k][1];
    }

    // epilogue: normalize, bias, residual, LayerNorm, ELU
    const float inv_l = 1.0f / l;
    const float4 xv0 = *(const float4*)&x[(size_t)d * TOT + 8 * ln];
    const float4 xv1 = *(const float4*)&x[(size_t)d * TOT + 8 * ln + 4];
    const float4 bi0 = *(const float4*)&bias[8 * ln];
    const float4 bi1 = *(const float4*)&bias[8 * ln + 4];
    float v[8];
    v[0] = fmaf(acc[0], inv_l, bi0.x + xv0.x);
    v[1] = fmaf(acc[1], inv_l, bi0.y + xv0.y);
    v[2] = fmaf(acc[2], inv_l, bi0.z + xv0.z);
    v[3] = fmaf(acc[3], inv_l, bi0.w + xv0.w);
    v[4] = fmaf(acc[4], inv_l, bi1.x + xv1.x);
    v[5] = fmaf(acc[5], inv_l, bi1.y + xv1.y);
    v[6] = fmaf(acc[6], inv_l, bi1.z + xv1.z);
    v[7] = fmaf(acc[7], inv_l, bi1.w + xv1.w);
    float sum = 0.f, sq = 0.f;
#pragma unroll
    for (int k = 0; k < 8; ++k) { sum += v[k]; sq = fmaf(v[k], v[k], sq); }
#pragma unroll
    for (int off = 1; off <= 8; off <<= 1) {
        sum += __shfl_xor(sum, off, 64);
        sq  += __shfl_xor(sq,  off, 64);
    }
    const float mu  = sum * (1.0f / TOT);
    const float var = sq * (1.0f / TOT) - mu * mu;
    const float inv = rsqrtf(var + LN_EPS);
    const float4 g0 = *(const float4*)&g[8 * ln];
    const float4 g1 = *(const float4*)&g[8 * ln + 4];
    const float4 b0 = *(const float4*)&bvec[8 * ln];
    const float4 b1 = *(const float4*)&bvec[8 * ln + 4];
    float y[8];
    y[0] = (v[0] - mu) * inv * g0.x + b0.x;
    y[1] = (v[1] - mu) * inv * g0.y + b0.y;
    y[2] = (v[2] - mu) * inv * g0.z + b0.z;
    y[3] = (v[3] - mu) * inv * g0.w + b0.w;
    y[4] = (v[4] - mu) * inv * g1.x + b1.x;
    y[5] = (v[5] - mu) * inv * g1.y + b1.y;
    y[6] = (v[6] - mu) * inv * g1.z + b1.z;
    y[7] = (v[7] - mu) * inv * g1.w + b1.w;
#pragma unroll
    for (int k = 0; k < 8; ++k) y[k] = y[k] > 0.f ? y[k] : __expf(y[k]) - 1.f;
    if (q < 2) {
        float4 o = (q == 0) ? make_float4(y[0], y[1], y[2], y[3])
                            : make_float4(y[4], y[5], y[6], y[7]);
        *(float4*)&out[(size_t)d * TOT + 8 * ln + 4 * q] = o;
    }
}

extern "C" void kernel_launch(void* const* d_in, const int* in_sizes, int n_in,
                              void* d_out, int out_size, void* d_ws, size_t ws_size,
                              hipStream_t stream) {
    const float* x    = (const float*)d_in[0];
    const int*   ei   = (const int*)d_in[1];
    const float* Wl   = (const float*)d_in[2];
    const float* bl   = (const float*)d_in[3];
    const float* Wr   = (const float*)d_in[4];
    const float* br   = (const float*)d_in[5];
    const float* att  = (const float*)d_in[6];
    const float* bias = (const float*)d_in[7];
    const float* ln_g = (const float*)d_in[8];
    const float* ln_b = (const float*)d_in[9];
    const int* srcs = ei;
    const int* dsts = ei + E_EDGES;

    unsigned* xlb = (unsigned*)d_ws;                          // N*64 dwords (f16 pairs)
    unsigned* xrb = xlb + (size_t)N_NODES * 64;               // N*64 dwords (f16 pairs)
    int*   rowptr     = (int*)(xrb + (size_t)N_NODES * 64);   // N+1
    unsigned* pub     = (unsigned*)(rowptr + N_NODES + 1);    // 196 lookback words (+pad)
    unsigned* WT      = (unsigned*)(pub + SCAN_NBLK + 3);     // 256*64 dwords (8B-aligned)
    unsigned char* HP = (unsigned char*)(WT + 256 * 64);      // 64*N u8 (3.2 MB)
    unsigned short* sorted16 = (unsigned short*)(HP + (size_t)HIST_NBLK * N_NODES); // M+32 u16
    unsigned char*  rank8    = (unsigned char*)(sorted16 + M_TOTAL + 32);           // M u8

    wthist_kernel<<<64 + HIST_NBLK, 256, 0, stream>>>(dsts, Wl, Wr, WT, HP, rank8, pub);
    scan_kernel<<<SCAN_NBLK, 256, 0, stream>>>(HP, rowptr, pub, sorted16);
    gemmscatter_kernel<<<GEMM_NBLK + SCAT_NBLK, 256, 0, stream>>>(
        x, WT, bl, br, xlb, xrb, srcs, dsts, rowptr, HP, rank8, sorted16);
    gat_kernel<<<N_NODES, 64, 0, stream>>>(rowptr, sorted16, xlb, xrb, att, x,
                                           bias, ln_g, ln_b, (float*)d_out);
}